// Round 11
// baseline (1173.548 us; speedup 1.0000x reference)
//
#include <hip/hip_runtime.h>
#include <hip/hip_bf16.h>
#include <stdint.h>

#define BB 8
#define CC 512
#define NN 4096
#define QB 128
#define KB 64
#define D4 2048
#define NT (NN / KB)   // 64

typedef short bf8 __attribute__((ext_vector_type(8)));
typedef float f32x4 __attribute__((ext_vector_type(4)));

__device__ __forceinline__ uint16_t f2bf(float f) {
  uint32_t u = __builtin_bit_cast(uint32_t, f);
  u = (u + 0x7FFFu + ((u >> 16) & 1u)) >> 16;
  return (uint16_t)u;
}
__device__ __forceinline__ float bf2f(uint16_t u) {
  return __builtin_bit_cast(float, (uint32_t)u << 16);
}

__device__ __forceinline__ void gl_lds16(const void* g, void* l) {
  __builtin_amdgcn_global_load_lds((__attribute__((address_space(1))) void*)g,
                                   (__attribute__((address_space(3))) void*)l, 16, 0, 0);
}

// [B,C,N] fp32 -> [B,N,C] bf16 (optional scale folded in)
__global__ __launch_bounds__(256) void transpose_cast_k(const float* __restrict__ src,
                                                        uint16_t* __restrict__ dst,
                                                        float scale) {
  __shared__ float tile[32][33];
  int b = blockIdx.z;
  int n0 = blockIdx.x * 32, c0 = blockIdx.y * 32;
  int tx = threadIdx.x & 31, ty = threadIdx.x >> 5;
  const float* s = src + ((size_t)b * CC + c0) * NN + n0;
#pragma unroll
  for (int i = 0; i < 4; i++) {
    int c = ty + i * 8;
    tile[tx][c] = s[(size_t)c * NN + tx];
  }
  __syncthreads();
  uint16_t* d = dst + ((size_t)b * NN + n0) * CC + c0;
#pragma unroll
  for (int i = 0; i < 4; i++) {
    int n = ty + i * 8;
    d[(size_t)n * CC + tx] = f2bf(tile[n][tx] * scale);
  }
}

__global__ __launch_bounds__(256) void cast_k(const float* __restrict__ in,
                                              uint16_t* __restrict__ out, int n) {
  int i = (blockIdx.x * 256 + threadIdx.x) * 4;
  if (i >= n) return;
  float4 v = *(const float4*)(in + i);
  ushort4 o;
  o.x = f2bf(v.x); o.y = f2bf(v.y); o.z = f2bf(v.z); o.w = f2bf(v.w);
  *(ushort4*)(out + i) = o;
}

// Fused flash-attention + FFN at QB=128: 256 blocks = 1/CU, ONE grid round,
// 3 barriers x 64 iters. Wave owns 16 q-rows (QK: full 64-col strip) and
// 64 channels x 128 n (PV acc = 128 AGPR). S bf16 in SP, P overwrites S in
// place (R6-validated). K dbuf, DMA issued at phase-1 top (full-iter flight).
// V and P fragments loaded just-in-time to stay under the 256-reg budget.
// O -> global ws; FFN (fused) reads O/W1/W2 from L2, two 64-token halves.
__global__ __launch_bounds__(512) __attribute__((amdgpu_waves_per_eu(2, 2))) void attn_ffn_k(
    const uint16_t* __restrict__ Qt, const uint16_t* __restrict__ Kt,
    const uint16_t* __restrict__ Vc, const uint16_t* __restrict__ W1b,
    const uint16_t* __restrict__ W2b, const float* __restrict__ b1,
    const float* __restrict__ b2, const float* __restrict__ gma,
    const float* __restrict__ qry, uint16_t* __restrict__ Ob,
    float* __restrict__ out) {
  __shared__ __attribute__((aligned(16))) uint16_t Ks[2][KB][CC];  // 128 KB dbuf; FFN Hs overlay
  __shared__ __attribute__((aligned(16))) uint16_t SP[QB][72];     // 18 KB: S(bf16) -> P in place
  __shared__ float lst[QB];
  __shared__ float rsc[QB];  // total 150528 B -> 1 block/CU

  const int bid = blockIdx.x + gridDim.x * blockIdx.y;
  const int b = bid & 7;           // batch == XCD round-robin
  const int n0 = (bid >> 3) * QB;  // 32 q-tiles of 128
  const int tid = threadIdx.x;
  const int lane = tid & 63, wid = tid >> 6;
  const int lhi = lane >> 4, llo = lane & 15;
  const int r7 = llo & 7;

  // Q fragments -> registers: wave owns q-rows wid*16 .. wid*16+15
  bf8 qf[16];
  {
    const uint16_t* qsrc = Qt + ((size_t)b * NN + n0 + wid * 16 + llo) * CC + lhi * 8;
#pragma unroll
    for (int kc = 0; kc < 16; kc++) qf[kc] = *(const bf8*)(qsrc + kc * 32);
  }

  // DMA K(0) -> Ks[0]
#pragma unroll
  for (int j = 0; j < 8; j++) {
    const int r = wid * 8 + j;
    gl_lds16(Kt + ((size_t)b * NN + r) * CC + ((lane ^ (r & 7)) << 3), &Ks[0][r][0]);
  }

  const f32x4 vzero = {0.f, 0.f, 0.f, 0.f};
  f32x4 acc[4][8];  // [ch-tile][n-tile] -> 128 AGPR
#pragma unroll
  for (int i = 0; i < 4; i++)
#pragma unroll
    for (int j = 0; j < 8; j++) acc[i][j] = vzero;

  const uint16_t* vbase = Vc + ((size_t)b * CC + wid * 64 + llo) * NN + lhi * 8;
  const int srow = tid >> 2, sj = tid & 3;  // softmax: 4 threads/row, 16 elems each
  float m_run = -__builtin_inff(), l_run = 0.f;

  for (int t = 0; t < NT; t++) {
    const int cur = t & 1;
    // B1: K(t) ready (drains DMA); P(t-1) reads finished wave-locally before here
    asm volatile("s_waitcnt vmcnt(0)" ::: "memory");
    __builtin_amdgcn_s_barrier();

    // DMA K(t+1) into other buffer — flies the whole iteration
    if (t + 1 < NT) {
#pragma unroll
      for (int j = 0; j < 8; j++) {
        const int r = wid * 8 + j;
        gl_lds16(Kt + ((size_t)b * NN + (t + 1) * KB + r) * CC + ((lane ^ (r & 7)) << 3),
                 &Ks[cur ^ 1][r][0]);
      }
    }
    __builtin_amdgcn_sched_barrier(0);

    // QK(t): wave computes S rows wid*16..+16 x all 64 cols (4 col-tiles)
    {
      const uint16_t* kr0 = &Ks[cur][0 + llo][0];
      const uint16_t* kr1 = &Ks[cur][16 + llo][0];
      const uint16_t* kr2 = &Ks[cur][32 + llo][0];
      const uint16_t* kr3 = &Ks[cur][48 + llo][0];
      f32x4 s0 = vzero, s1 = vzero, s2 = vzero, s3 = vzero;
      __builtin_amdgcn_s_setprio(1);
#pragma unroll
      for (int kc = 0; kc < 16; kc++) {
        const int g = ((kc * 4 + lhi) ^ r7) << 3;
        s0 = __builtin_amdgcn_mfma_f32_16x16x32_bf16(qf[kc], *(const bf8*)(kr0 + g), s0, 0, 0, 0);
        s1 = __builtin_amdgcn_mfma_f32_16x16x32_bf16(qf[kc], *(const bf8*)(kr1 + g), s1, 0, 0, 0);
        s2 = __builtin_amdgcn_mfma_f32_16x16x32_bf16(qf[kc], *(const bf8*)(kr2 + g), s2, 0, 0, 0);
        s3 = __builtin_amdgcn_mfma_f32_16x16x32_bf16(qf[kc], *(const bf8*)(kr3 + g), s3, 0, 0, 0);
      }
      __builtin_amdgcn_s_setprio(0);
      const int nr = wid * 16 + lhi * 4;
#pragma unroll
      for (int r = 0; r < 4; r++) {
        SP[nr + r][llo] = f2bf(s0[r]);
        SP[nr + r][16 + llo] = f2bf(s1[r]);
        SP[nr + r][32 + llo] = f2bf(s2[r]);
        SP[nr + r][48 + llo] = f2bf(s3[r]);
      }
    }
    // B2: S visible
    asm volatile("s_waitcnt lgkmcnt(0)" ::: "memory");
    __builtin_amdgcn_s_barrier();

    // softmax(t): 4 threads/row, 16 elems each; P overwrites S in place
    {
      const bf8 a0 = *(const bf8*)&SP[srow][sj * 16];
      const bf8 a1 = *(const bf8*)&SP[srow][sj * 16 + 8];
      float sv[16];
#pragma unroll
      for (int k2 = 0; k2 < 8; k2++) {
        sv[k2] = bf2f((uint16_t)a0[k2]);
        sv[8 + k2] = bf2f((uint16_t)a1[k2]);
      }
      float mx = sv[0];
#pragma unroll
      for (int k2 = 1; k2 < 16; k2++) mx = fmaxf(mx, sv[k2]);
      mx = fmaxf(mx, __shfl_xor(mx, 1, 4));
      mx = fmaxf(mx, __shfl_xor(mx, 2, 4));
      const float nm = fmaxf(m_run, mx);
      const float rs = __expf(m_run - nm);
      float psum = 0.f;
      bf8 p0, p1;
#pragma unroll
      for (int k2 = 0; k2 < 8; k2++) {
        float pa = __expf(sv[k2] - nm);
        float pb = __expf(sv[8 + k2] - nm);
        psum += pa + pb;
        p0[k2] = (short)f2bf(pa);
        p1[k2] = (short)f2bf(pb);
      }
      *(bf8*)&SP[srow][sj * 16] = p0;
      *(bf8*)&SP[srow][sj * 16 + 8] = p1;
      psum += __shfl_xor(psum, 1, 4);
      psum += __shfl_xor(psum, 2, 4);
      l_run = l_run * rs + psum;
      m_run = nm;
      if (sj == 0) {
        rsc[srow] = rs;
        if (t == NT - 1) lst[srow] = l_run;
      }
    }
    // B3: P + rsc visible (DMA keeps flying)
    asm volatile("s_waitcnt lgkmcnt(0)" ::: "memory");
    __builtin_amdgcn_s_barrier();

    // PV(t): rescale then acc[c][n] += V[c][m]·P[n][m]; V/P loaded just-in-time
    {
      float rsn[8];
#pragma unroll
      for (int nt = 0; nt < 8; nt++) rsn[nt] = rsc[nt * 16 + llo];
#pragma unroll
      for (int rt = 0; rt < 4; rt++)
#pragma unroll
        for (int nt = 0; nt < 8; nt++) acc[rt][nt] *= rsn[nt];

      __builtin_amdgcn_s_setprio(1);
#pragma unroll
      for (int ks = 0; ks < 2; ks++) {
        bf8 av[4];
#pragma unroll
        for (int rt = 0; rt < 4; rt++)
          av[rt] = *(const bf8*)(vbase + (size_t)rt * 16 * NN + t * KB + ks * 32);
#pragma unroll
        for (int ntp = 0; ntp < 4; ntp++) {
          const bf8 bp0 = *(const bf8*)&SP[(ntp * 2) * 16 + llo][(ks * 4 + lhi) * 8];
          const bf8 bp1 = *(const bf8*)&SP[(ntp * 2 + 1) * 16 + llo][(ks * 4 + lhi) * 8];
#pragma unroll
          for (int rt = 0; rt < 4; rt++) {
            acc[rt][ntp * 2] = __builtin_amdgcn_mfma_f32_16x16x32_bf16(av[rt], bp0, acc[rt][ntp * 2], 0, 0, 0);
            acc[rt][ntp * 2 + 1] = __builtin_amdgcn_mfma_f32_16x16x32_bf16(av[rt], bp1, acc[rt][ntp * 2 + 1], 0, 0, 0);
          }
        }
      }
      __builtin_amdgcn_s_setprio(0);
    }
  }

  // normalize + write O (bf16 [B][N][C]) to global ws
  {
    float invl[8];
#pragma unroll
    for (int nt = 0; nt < 8; nt++) invl[nt] = 1.0f / lst[nt * 16 + llo];
#pragma unroll
    for (int rt = 0; rt < 4; rt++)
#pragma unroll
      for (int nt = 0; nt < 8; nt++) {
        ushort4 o4;
        o4.x = f2bf(acc[rt][nt][0] * invl[nt]);
        o4.y = f2bf(acc[rt][nt][1] * invl[nt]);
        o4.z = f2bf(acc[rt][nt][2] * invl[nt]);
        o4.w = f2bf(acc[rt][nt][3] * invl[nt]);
        *(ushort4*)(Ob + ((size_t)b * NN + n0 + nt * 16 + llo) * CC + wid * 64 + rt * 16 + lhi * 4) = o4;
      }
  }
  asm volatile("s_waitcnt vmcnt(0)" ::: "memory");
  __builtin_amdgcn_s_barrier();  // O visible block-wide (same-XCD L2)

  // ---- FFN: two 64-token halves; O + weights stream from L2; Hs on Ks[1] ----
  uint16_t(*Hs)[CC] = (uint16_t(*)[CC]) & Ks[1][0][0];
  const float g = gma[0];

  for (int h = 0; h < 2; h++) {
    const uint16_t* ObB = Ob + ((size_t)b * NN + n0 + h * 64) * CC;
    f32x4 facc[4][4];
#pragma unroll
    for (int i = 0; i < 4; i++)
#pragma unroll
      for (int j = 0; j < 4; j++) facc[i][j] = vzero;

    for (int qtr = 0; qtr < 4; qtr++) {
      const int dq0 = qtr * 512;
      f32x4 hacc[4][4];
#pragma unroll
      for (int i = 0; i < 4; i++)
#pragma unroll
        for (int j = 0; j < 4; j++) hacc[i][j] = vzero;
      __syncthreads();  // prev qtr's Hs reads done
      __builtin_amdgcn_s_setprio(1);
#pragma unroll 2
      for (int kc8 = 0; kc8 < 64; kc8 += 4) {
        bf8 bo[4], aw[4];
#pragma unroll
        for (int nt = 0; nt < 4; nt++)
          bo[nt] = *(const bf8*)(ObB + (size_t)(nt * 16 + llo) * CC + (kc8 + lhi) * 8);
#pragma unroll
        for (int dt = 0; dt < 4; dt++) {
          const int d = dq0 + wid * 64 + dt * 16 + llo;
          aw[dt] = *(const bf8*)(W1b + (size_t)d * CC + (kc8 + lhi) * 8);
        }
#pragma unroll
        for (int dt = 0; dt < 4; dt++)
#pragma unroll
          for (int nt = 0; nt < 4; nt++)
            hacc[dt][nt] = __builtin_amdgcn_mfma_f32_16x16x32_bf16(aw[dt], bo[nt], hacc[dt][nt], 0, 0, 0);
      }
      __builtin_amdgcn_s_setprio(0);
#pragma unroll
      for (int dt = 0; dt < 4; dt++) {
        const int dg = dq0 + wid * 64 + dt * 16 + lhi * 4;
        const float4 b1v = *(const float4*)(b1 + dg);
#pragma unroll
        for (int nt = 0; nt < 4; nt++) {
          ushort4 h4;
          h4.x = f2bf(fmaxf(hacc[dt][nt][0] + b1v.x, 0.f));
          h4.y = f2bf(fmaxf(hacc[dt][nt][1] + b1v.y, 0.f));
          h4.z = f2bf(fmaxf(hacc[dt][nt][2] + b1v.z, 0.f));
          h4.w = f2bf(fmaxf(hacc[dt][nt][3] + b1v.w, 0.f));
          const int gch = wid * 8 + dt * 2 + (lhi >> 1);
          *(ushort4*)(&Hs[nt * 16 + llo][0] + ((gch ^ r7) << 3) + ((lhi & 1) << 2)) = h4;
        }
      }
      __syncthreads();  // hidden quarter ready
      __builtin_amdgcn_s_setprio(1);
#pragma unroll 2
      for (int kd8 = 0; kd8 < 64; kd8 += 4) {
        bf8 ah[4], bw[4];
        const int gof = ((kd8 + lhi) ^ r7) << 3;
#pragma unroll
        for (int nt = 0; nt < 4; nt++) ah[nt] = *(const bf8*)(&Hs[nt * 16 + llo][0] + gof);
#pragma unroll
        for (int ct = 0; ct < 4; ct++) {
          const int c = wid * 64 + ct * 16 + llo;
          bw[ct] = *(const bf8*)(W2b + (size_t)c * D4 + dq0 + (kd8 + lhi) * 8);
        }
#pragma unroll
        for (int nt = 0; nt < 4; nt++)
#pragma unroll
          for (int ct = 0; ct < 4; ct++)
            facc[nt][ct] = __builtin_amdgcn_mfma_f32_16x16x32_bf16(ah[nt], bw[ct], facc[nt][ct], 0, 0, 0);
      }
      __builtin_amdgcn_s_setprio(0);
    }

    // epilogue for this half: out[b,c,n] = (facc + b2[c])*gamma + query
#pragma unroll
    for (int nt = 0; nt < 4; nt++) {
      const int n = n0 + h * 64 + nt * 16 + lhi * 4;
#pragma unroll
      for (int ct = 0; ct < 4; ct++) {
        const int c = wid * 64 + ct * 16 + llo;
        const float b2c = b2[c];
        const size_t off = ((size_t)b * CC + c) * NN + n;
        const float4 q4 = *(const float4*)(qry + off);
        float4 o4;
        o4.x = (facc[nt][ct][0] + b2c) * g + q4.x;
        o4.y = (facc[nt][ct][1] + b2c) * g + q4.y;
        o4.z = (facc[nt][ct][2] + b2c) * g + q4.z;
        o4.w = (facc[nt][ct][3] + b2c) * g + q4.w;
        *(float4*)(out + off) = o4;
      }
    }
    __syncthreads();  // Hs reads done before next half reuses it
  }
}

extern "C" void kernel_launch(void* const* d_in, const int* in_sizes, int n_in,
                              void* d_out, int out_size, void* d_ws, size_t ws_size,
                              hipStream_t stream) {
  const float* q = (const float*)d_in[0];
  const float* k = (const float*)d_in[1];
  const float* v = (const float*)d_in[2];
  const float* w1 = (const float*)d_in[3];
  const float* b1 = (const float*)d_in[4];
  const float* w2 = (const float*)d_in[5];
  const float* b2 = (const float*)d_in[6];
  const float* gm = (const float*)d_in[7];
  float* out = (float*)d_out;

  uint16_t* Qt = (uint16_t*)d_ws;                    // [B][N][C] bf16 (pre-scaled)  32 MB
  uint16_t* Kt = Qt + (size_t)BB * NN * CC;          // [B][N][C] bf16               32 MB
  uint16_t* Vc = Kt + (size_t)BB * NN * CC;          // [B][C][N] bf16               32 MB
  uint16_t* W1b = Vc + (size_t)BB * NN * CC;         // [2048][512] bf16              2 MB
  uint16_t* W2b = W1b + (size_t)D4 * CC;             // [512][2048] bf16              2 MB
  uint16_t* Ob = W2b + (size_t)CC * D4;              // [B][N][C] bf16 (O)           32 MB

  dim3 tgrid(NN / 32, CC / 32, BB);
  transpose_cast_k<<<tgrid, 256, 0, stream>>>(q, Qt, 0.044194173824159216f);
  transpose_cast_k<<<tgrid, 256, 0, stream>>>(k, Kt, 1.0f);
  cast_k<<<(BB * CC * NN / 4 + 255) / 256, 256, 0, stream>>>(v, Vc, BB * CC * NN);
  cast_k<<<(D4 * CC / 4 + 255) / 256, 256, 0, stream>>>(w1, W1b, D4 * CC);
  cast_k<<<(CC * D4 / 4 + 255) / 256, 256, 0, stream>>>(w2, W2b, CC * D4);
  attn_ffn_k<<<dim3(NN / QB, BB), 512, 0, stream>>>(Qt, Kt, Vc, W1b, W2b, b1, b2, gm, q, Ob, out);
}